// Round 1
// baseline (45.152 us; speedup 1.0000x reference)
//
#include <hip/hip_runtime.h>

#define HH 1080
#define WW 1920
#define NPIX (HH * WW)

// ws layout: ws[0..11] = T rows 0..2 (3x4), ws[12..20] = K_inv (3x3 row-major)
__global__ void setup_mats(const float* __restrict__ f1, const float* __restrict__ f2,
                           const float* __restrict__ Kmat, float* __restrict__ ws) {
    // single thread: invert f2 (4x4, Gauss-Jordan w/ partial pivot, double), T = f1 @ inv(f2)
    double a[4][8];
    for (int i = 0; i < 4; ++i) {
        for (int j = 0; j < 4; ++j) a[i][j] = (double)f2[i * 4 + j];
        for (int j = 0; j < 4; ++j) a[i][4 + j] = (i == j) ? 1.0 : 0.0;
    }
    for (int col = 0; col < 4; ++col) {
        int piv = col;
        double best = fabs(a[col][col]);
        for (int r = col + 1; r < 4; ++r) {
            double v = fabs(a[r][col]);
            if (v > best) { best = v; piv = r; }
        }
        if (piv != col) {
            for (int j = 0; j < 8; ++j) { double t = a[col][j]; a[col][j] = a[piv][j]; a[piv][j] = t; }
        }
        double inv = 1.0 / a[col][col];
        for (int j = 0; j < 8; ++j) a[col][j] *= inv;
        for (int r = 0; r < 4; ++r) {
            if (r == col) continue;
            double f = a[r][col];
            if (f != 0.0)
                for (int j = 0; j < 8; ++j) a[r][j] -= f * a[col][j];
        }
    }
    for (int i = 0; i < 3; ++i)
        for (int j = 0; j < 4; ++j) {
            double s = 0.0;
            for (int k = 0; k < 4; ++k) s += (double)f1[i * 4 + k] * a[k][4 + j];
            ws[i * 4 + j] = (float)s;
        }
    // K_inv via adjugate (double)
    double k00 = Kmat[0], k01 = Kmat[1], k02 = Kmat[2];
    double k10 = Kmat[3], k11 = Kmat[4], k12 = Kmat[5];
    double k20 = Kmat[6], k21 = Kmat[7], k22 = Kmat[8];
    double det = k00 * (k11 * k22 - k12 * k21) - k01 * (k10 * k22 - k12 * k20) +
                 k02 * (k10 * k21 - k11 * k20);
    double id = 1.0 / det;
    float* ki = ws + 12;
    ki[0] = (float)((k11 * k22 - k12 * k21) * id);
    ki[1] = (float)(-(k01 * k22 - k02 * k21) * id);
    ki[2] = (float)((k01 * k12 - k02 * k11) * id);
    ki[3] = (float)(-(k10 * k22 - k12 * k20) * id);
    ki[4] = (float)((k00 * k22 - k02 * k20) * id);
    ki[5] = (float)(-(k00 * k12 - k02 * k10) * id);
    ki[6] = (float)((k10 * k21 - k11 * k20) * id);
    ki[7] = (float)(-(k00 * k21 - k01 * k20) * id);
    ki[8] = (float)((k00 * k11 - k01 * k10) * id);
}

__global__ __launch_bounds__(256) void warp_main(
    const float* __restrict__ c1, const float* __restrict__ d1,
    const float* __restrict__ Kmat, const float* __restrict__ ws,
    float* __restrict__ out) {
    int p = blockIdx.x * blockDim.x + threadIdx.x;
    if (p >= NPIX) return;
    int h = p / WW;
    int w = p - h * WW;

    // uniform-address loads (compiler scalarizes to s_load; all L1-hit anyway)
    float T00 = ws[0], T01 = ws[1], T02 = ws[2], T03 = ws[3];
    float T10 = ws[4], T11 = ws[5], T12 = ws[6], T13 = ws[7];
    float T20 = ws[8], T21 = ws[9], T22 = ws[10], T23 = ws[11];
    float ki0 = ws[12], ki1 = ws[13], ki2 = ws[14];
    float ki3 = ws[15], ki4 = ws[16], ki5 = ws[17];
    float ki6 = ws[18], ki7 = ws[19], ki8 = ws[20];
    float K00 = Kmat[0], K01 = Kmat[1], K02 = Kmat[2];
    float K10 = Kmat[3], K11 = Kmat[4], K12 = Kmat[5];
    float K20 = Kmat[6], K21 = Kmat[7], K22 = Kmat[8];

    float u = (float)w, v = (float)h;
    // ray = K_inv @ [u, v, 1]
    float rx = ki0 * u + ki1 * v + ki2;
    float ry = ki3 * u + ki4 * v + ki5;
    float rz = ki6 * u + ki7 * v + ki8;
    float d = d1[p];
    float bx = d * rx, by = d * ry, bz = d * rz;
    // pt = R @ b + t
    float px = T00 * bx + T01 * by + T02 * bz + T03;
    float py = T10 * bx + T11 * by + T12 * bz + T13;
    float pz = T20 * bx + T21 * by + T22 * bz + T23;
    // warped = K @ pt
    float wxp = K00 * px + K01 * py + K02 * pz;
    float wyp = K10 * px + K11 * py + K12 * pz;
    float wzp = K20 * px + K21 * py + K22 * pz;
    float sx = wxp / wzp;
    float sy = wyp / wzp;
    float nx = sx * (2.0f / WW) - 1.0f;
    float ny = sy * (2.0f / HH) - 1.0f;

    // normalized_warps [1,H,W,2]
    float2* nw = (float2*)(out + (size_t)NPIX * 3);
    nw[p] = make_float2(nx, ny);
    // keep_mask [H,W]
    float keep = (nx < 1.0f && ny < 1.0f && nx > -1.0f && ny > -1.0f) ? 1.0f : 0.0f;
    out[(size_t)NPIX * 5 + p] = keep;

    // bilinear grid_sample, zeros padding, align_corners=False
    float x = (nx + 1.0f) * (WW * 0.5f) - 0.5f;
    float y = (ny + 1.0f) * (HH * 0.5f) - 0.5f;
    float x0f = floorf(x), y0f = floorf(y);
    float fx1 = x - x0f, fx0 = 1.0f - fx1;
    float fy1 = y - y0f, fy0 = 1.0f - fy1;

    float r0 = 0.0f, r1 = 0.0f, r2 = 0.0f;
#pragma unroll
    for (int dy = 0; dy < 2; ++dy) {
#pragma unroll
        for (int dx = 0; dx < 2; ++dx) {
            float xf = x0f + (float)dx;
            float yf = y0f + (float)dy;
            bool valid = (xf >= 0.0f) && (xf < (float)WW) && (yf >= 0.0f) && (yf < (float)HH);
            if (valid) {
                int xi = (int)xf;
                int yi = (int)yf;
                const float* src = c1 + ((size_t)yi * WW + xi) * 3;
                float wgt = (dy ? fy1 : fy0) * (dx ? fx1 : fx0);
                r0 += src[0] * wgt;
                r1 += src[1] * wgt;
                r2 += src[2] * wgt;
            }
        }
    }
    float* res = out + (size_t)p * 3;
    res[0] = r0;
    res[1] = r1;
    res[2] = r2;
}

extern "C" void kernel_launch(void* const* d_in, const int* in_sizes, int n_in,
                              void* d_out, int out_size, void* d_ws, size_t ws_size,
                              hipStream_t stream) {
    const float* f1 = (const float*)d_in[0];
    const float* f2 = (const float*)d_in[1];
    const float* K = (const float*)d_in[2];
    // d_in[3] is _K (same values)
    const float* c1 = (const float*)d_in[4];
    const float* d1 = (const float*)d_in[5];
    float* out = (float*)d_out;
    float* ws = (float*)d_ws;

    setup_mats<<<1, 1, 0, stream>>>(f1, f2, K, ws);
    int threads = 256;
    int blocks = (NPIX + threads - 1) / threads;
    warp_main<<<blocks, threads, 0, stream>>>(c1, d1, K, ws, out);
}

// Round 2
// 33.549 us; speedup vs baseline: 1.3459x; 1.3459x over previous
//
#include <hip/hip_runtime.h>

#define HH 1080
#define WW 1920
#define NPIX (HH * WW)
#define TW 64
#define TH 4
#define TILES_X (WW / TW)   // 30
#define TILES_Y (HH / TH)   // 270
#define NWG (TILES_X * TILES_Y)  // 8100

// ws layout: ws[0..11] = T rows 0..2 (3x4), ws[12..20] = K_inv (3x3 row-major)
__global__ void setup_mats(const float* __restrict__ f1, const float* __restrict__ f2,
                           const float* __restrict__ Kmat, float* __restrict__ ws) {
    // single thread: invert f2 (4x4, Gauss-Jordan w/ partial pivot, double), T = f1 @ inv(f2)
    double a[4][8];
    for (int i = 0; i < 4; ++i) {
        for (int j = 0; j < 4; ++j) a[i][j] = (double)f2[i * 4 + j];
        for (int j = 0; j < 4; ++j) a[i][4 + j] = (i == j) ? 1.0 : 0.0;
    }
    for (int col = 0; col < 4; ++col) {
        int piv = col;
        double best = fabs(a[col][col]);
        for (int r = col + 1; r < 4; ++r) {
            double v = fabs(a[r][col]);
            if (v > best) { best = v; piv = r; }
        }
        if (piv != col) {
            for (int j = 0; j < 8; ++j) { double t = a[col][j]; a[col][j] = a[piv][j]; a[piv][j] = t; }
        }
        double inv = 1.0 / a[col][col];
        for (int j = 0; j < 8; ++j) a[col][j] *= inv;
        for (int r = 0; r < 4; ++r) {
            if (r == col) continue;
            double f = a[r][col];
            if (f != 0.0)
                for (int j = 0; j < 8; ++j) a[r][j] -= f * a[col][j];
        }
    }
    for (int i = 0; i < 3; ++i)
        for (int j = 0; j < 4; ++j) {
            double s = 0.0;
            for (int k = 0; k < 4; ++k) s += (double)f1[i * 4 + k] * a[k][4 + j];
            ws[i * 4 + j] = (float)s;
        }
    // K_inv via adjugate (double)
    double k00 = Kmat[0], k01 = Kmat[1], k02 = Kmat[2];
    double k10 = Kmat[3], k11 = Kmat[4], k12 = Kmat[5];
    double k20 = Kmat[6], k21 = Kmat[7], k22 = Kmat[8];
    double det = k00 * (k11 * k22 - k12 * k21) - k01 * (k10 * k22 - k12 * k20) +
                 k02 * (k10 * k21 - k11 * k20);
    double id = 1.0 / det;
    float* ki = ws + 12;
    ki[0] = (float)((k11 * k22 - k12 * k21) * id);
    ki[1] = (float)(-(k01 * k22 - k02 * k21) * id);
    ki[2] = (float)((k01 * k12 - k02 * k11) * id);
    ki[3] = (float)(-(k10 * k22 - k12 * k20) * id);
    ki[4] = (float)((k00 * k22 - k02 * k20) * id);
    ki[5] = (float)(-(k00 * k12 - k02 * k10) * id);
    ki[6] = (float)((k10 * k21 - k11 * k20) * id);
    ki[7] = (float)(-(k00 * k21 - k01 * k20) * id);
    ki[8] = (float)((k00 * k11 - k01 * k10) * id);
}

__global__ __launch_bounds__(256) void warp_main(
    const float* __restrict__ c1, const float* __restrict__ d1,
    const float* __restrict__ Kmat, const float* __restrict__ ws,
    float* __restrict__ out) {
    // bijective XCD swizzle (m204): XCD x owns a contiguous band of tiles
    int b = blockIdx.x;
    int xcd = b & 7;
    int idx = b >> 3;
    const int q = NWG >> 3;       // 1012
    const int r = NWG & 7;        // 4
    int swz = (xcd < r ? xcd * (q + 1) : r * (q + 1) + (xcd - r) * q) + idx;

    int tyid = swz / TILES_X;
    int txid = swz - tyid * TILES_X;
    int tx = threadIdx.x & (TW - 1);
    int ty = threadIdx.x >> 6;
    int w = txid * TW + tx;
    int h = tyid * TH + ty;
    int p = h * WW + w;

    float T00 = ws[0], T01 = ws[1], T02 = ws[2], T03 = ws[3];
    float T10 = ws[4], T11 = ws[5], T12 = ws[6], T13 = ws[7];
    float T20 = ws[8], T21 = ws[9], T22 = ws[10], T23 = ws[11];
    float ki0 = ws[12], ki1 = ws[13], ki2 = ws[14];
    float ki3 = ws[15], ki4 = ws[16], ki5 = ws[17];
    float ki6 = ws[18], ki7 = ws[19], ki8 = ws[20];
    float K00 = Kmat[0], K01 = Kmat[1], K02 = Kmat[2];
    float K10 = Kmat[3], K11 = Kmat[4], K12 = Kmat[5];
    float K20 = Kmat[6], K21 = Kmat[7], K22 = Kmat[8];

    float u = (float)w, v = (float)h;
    // ray = K_inv @ [u, v, 1]
    float rx = ki0 * u + ki1 * v + ki2;
    float ry = ki3 * u + ki4 * v + ki5;
    float rz = ki6 * u + ki7 * v + ki8;
    float d = d1[p];
    float bx = d * rx, by = d * ry, bz = d * rz;
    // pt = R @ b + t
    float px = T00 * bx + T01 * by + T02 * bz + T03;
    float py = T10 * bx + T11 * by + T12 * bz + T13;
    float pz = T20 * bx + T21 * by + T22 * bz + T23;
    // warped = K @ pt
    float wxp = K00 * px + K01 * py + K02 * pz;
    float wyp = K10 * px + K11 * py + K12 * pz;
    float wzp = K20 * px + K21 * py + K22 * pz;
    float sx = wxp / wzp;
    float sy = wyp / wzp;
    float nx = sx * (2.0f / WW) - 1.0f;
    float ny = sy * (2.0f / HH) - 1.0f;

    // normalized_warps [1,H,W,2] — nontemporal 8B store
    {
        float2 nv2 = make_float2(nx, ny);
        double bits = __builtin_bit_cast(double, nv2);
        __builtin_nontemporal_store(bits, (double*)(out + (size_t)NPIX * 3) + p);
    }
    // keep_mask [H,W]
    float keep = (nx < 1.0f && ny < 1.0f && nx > -1.0f && ny > -1.0f) ? 1.0f : 0.0f;
    __builtin_nontemporal_store(keep, out + (size_t)NPIX * 5 + p);

    // bilinear grid_sample, zeros padding, align_corners=False
    float x = (nx + 1.0f) * (WW * 0.5f) - 0.5f;
    float y = (ny + 1.0f) * (HH * 0.5f) - 0.5f;
    float x0f = floorf(x), y0f = floorf(y);
    float fx1 = x - x0f, fx0 = 1.0f - fx1;
    float fy1 = y - y0f, fy0 = 1.0f - fy1;

    float r0 = 0.0f, r1 = 0.0f, r2 = 0.0f;
#pragma unroll
    for (int dy = 0; dy < 2; ++dy) {
#pragma unroll
        for (int dx = 0; dx < 2; ++dx) {
            float xf = x0f + (float)dx;
            float yf = y0f + (float)dy;
            bool valid = (xf >= 0.0f) && (xf < (float)WW) && (yf >= 0.0f) && (yf < (float)HH);
            if (valid) {
                int xi = (int)xf;
                int yi = (int)yf;
                const float* src = c1 + ((size_t)yi * WW + xi) * 3;
                float wgt = (dy ? fy1 : fy0) * (dx ? fx1 : fx0);
                r0 += src[0] * wgt;
                r1 += src[1] * wgt;
                r2 += src[2] * wgt;
            }
        }
    }
    float* res = out + (size_t)p * 3;
    __builtin_nontemporal_store(r0, res + 0);
    __builtin_nontemporal_store(r1, res + 1);
    __builtin_nontemporal_store(r2, res + 2);
}

extern "C" void kernel_launch(void* const* d_in, const int* in_sizes, int n_in,
                              void* d_out, int out_size, void* d_ws, size_t ws_size,
                              hipStream_t stream) {
    const float* f1 = (const float*)d_in[0];
    const float* f2 = (const float*)d_in[1];
    const float* K = (const float*)d_in[2];
    // d_in[3] is _K (same values)
    const float* c1 = (const float*)d_in[4];
    const float* d1 = (const float*)d_in[5];
    float* out = (float*)d_out;
    float* ws = (float*)d_ws;

    setup_mats<<<1, 1, 0, stream>>>(f1, f2, K, ws);
    warp_main<<<NWG, 256, 0, stream>>>(c1, d1, K, ws, out);
}